// Round 1
// 2893.851 us; speedup vs baseline: 1.0251x; 1.0251x over previous
//
#include <hip/hip_runtime.h>
#include <hip/hip_bf16.h>
#include <math.h>

typedef __attribute__((ext_vector_type(8))) short short8;
typedef __attribute__((ext_vector_type(4))) float floatx4;

#define DEVFN static __device__ __forceinline__

constexpr int B = 128, T = 256, H = 512;
constexpr int OUTW = 121;
// fxHL slot row layout (per batch row, per time slot), elems:
//   hi: [x(3) win(60) pad(1) h1(512) h2(512)] = 1088
//   lo: cols 0..575 only (x,win,h1)           = 576
constexpr int SLOTW = 1664;              // row stride in elems (hi 1088 + lo 576)
constexpr int LOOF  = 1088;              // lo region offset within row
constexpr int SLOTE = B * SLOTW;         // elems per time slot
constexpr int NSLOT = T + 2;
constexpr int NG  = 2048;                // 4*H gate rows (interleaved n' = hcol*4+gate)
constexpr int K1  = 576,  K1C = 18;
constexpr int K2  = 1088, K2C = 34;
constexpr int KW1P = 584, KW2P = 1096;   // LDS weight row pads
constexpr int FSTR = 4;                  // flag stride (ints) — 16B pad per flag
// Sentinel: bf16-NaN pair. All real data (x gaussians, sigmoid/tanh outputs,
// exp of bounded args, blo residuals) is finite -> hi half never 0x7FFF.
constexpr unsigned int SENT = 0x7FFF7FFFu;

// ---- LDS offsets (bytes) ----
// G1 path. NOTE: hs/pp alias the Gsm region — window phase and GEMM phase are
// temporally disjoint (separated by barriers).
constexpr int O_WH1 = 0;                 // 32*584*2 = 37376
constexpr int O_WL1 = 37376;             // -> 74752
constexpr int O_W1S = 74752;             // 30*520*4 = 62400 -> 137152
constexpr int O_GSM = 137152;            // 32*65*4 = 8320 -> 145472
constexpr int O_HS  = 137152;            // 528*4 = 2112 (alias in Gsm; also winv)
constexpr int O_PP  = 139264;            // 240*4 = 960 (alias in Gsm)
constexpr int O_IPL = 145472;            // 30*4
constexpr int O_KL  = 145592;            // 10*4
constexpr int O_PHL = 145632;            // 64*4
constexpr int O_WAC = 145888;            // 240*4
constexpr int O_KPR = 146848;            // 10*4
constexpr int O_B1S = 146888;            // 30*4
constexpr int O_BIA = 147008;            // 32*4 -> 147136
constexpr int O_SENT = 147136;           // 64*60 fp32 = 15360 -> 162496
// G2 path:
constexpr int O_WH2 = 0;                 // 32*1096*2 = 70144
constexpr int O_WL2 = 70144;             // -> 140288
constexpr int O_GS2 = 140288;            // 8320 -> 148608
constexpr int O_BI2 = 148608;            // 128 -> 148736
constexpr int LDS_SZ = 162496;

DEVFN __hip_bfloat16 bhi(float v) { return __float2bfloat16(v); }
DEVFN __hip_bfloat16 blo(float v, __hip_bfloat16 h) { return __float2bfloat16(v - __bfloat162float(h)); }
DEVFN float bf2f(__hip_bfloat16 h) { return __bfloat162float(h); }
DEVFN float bfu(unsigned short u) {
  union { unsigned short u; __hip_bfloat16 h; } c; c.u = u; return __bfloat162float(c.h);
}
DEVFN unsigned short bbits(__hip_bfloat16 h) { union { __hip_bfloat16 h; unsigned short u; } c; c.h = h; return c.u; }
DEVFN unsigned int pack2(float a, float b) {
  return (unsigned int)bbits(bhi(a)) | ((unsigned int)bbits(bhi(b)) << 16);
}
DEVFN void ast(unsigned int* p, unsigned int v) {
  __hip_atomic_store(p, v, __ATOMIC_RELAXED, __HIP_MEMORY_SCOPE_AGENT);
}
DEVFN int ald(int* p) {
  return __hip_atomic_load(p, __ATOMIC_RELAXED, __HIP_MEMORY_SCOPE_AGENT);
}
DEVFN unsigned int uald(const unsigned int* p) {
  return __hip_atomic_load((unsigned int*)p, __ATOMIC_RELAXED, __HIP_MEMORY_SCOPE_AGENT);
}

// wait until flags[i*FSTR] >= target for i in [0,n) (n<=64); wave-coalesced polls
DEVFN void waitflags(int* flags, int n, int target) {
  if ((int)threadIdx.x < n) {
    int g = 0;
    while (ald(&flags[threadIdx.x * FSTR]) < target && g < (1 << 22)) { ++g; __builtin_amdgcn_s_sleep(1); }
  }
  asm volatile("" ::: "memory");
  __syncthreads();
}
// drain own stores, then publish flag value (single store, no atomic RMW)
DEVFN void flag_store(int* flag, int val) {
  asm volatile("s_waitcnt vmcnt(0)" ::: "memory");
  __syncthreads();
  if (threadIdx.x == 0)
    __hip_atomic_store(flag, val, __ATOMIC_RELAXED, __HIP_MEMORY_SCOPE_AGENT);
}

// ---------------- sentinel init ----------------
// Fill every dword that k_persist sentinel-polls: for slots 1..256, each row:
//   hi dwords 1..287 (win cols 2..63 + h1 cols 64..575)
//   lo dwords 1..287 (same cols, lo residual region)
// dword 0 (x pack, from k_pre) is real data and never sentinel.
__global__ __launch_bounds__(256) void k_sent(__hip_bfloat16* __restrict__ fxHL)
{
  int blk = blockIdx.x;                  // 0 .. 256*128-1
  int slot = (blk >> 7) + 1;             // 1..256
  int row  = blk & 127;
  unsigned int* rb = (unsigned int*)(fxHL + (size_t)slot * SLOTE + (size_t)row * SLOTW);
  for (int i = threadIdx.x; i < 287; i += 256) {
    rb[1 + i] = SENT;
    rb[(LOOF >> 1) + 1 + i] = SENT;
  }
}

// ---------------- precompute ----------------
__global__ __launch_bounds__(256) void k_pre(
    const float* __restrict__ x, const float* __restrict__ h1h, const float* __restrict__ h2h,
    const float* __restrict__ Wihc, const float* __restrict__ Whhc, const float* __restrict__ bc,
    const float* __restrict__ Wihl, const float* __restrict__ Whhl, const float* __restrict__ bl,
    const float* __restrict__ W2,
    __hip_bfloat16* __restrict__ fxHL,
    __hip_bfloat16* __restrict__ wc1, __hip_bfloat16* __restrict__ wc1l,
    __hip_bfloat16* __restrict__ wc2, __hip_bfloat16* __restrict__ wc2l,
    __hip_bfloat16* __restrict__ w2b, float* __restrict__ bi1, float* __restrict__ bi2,
    int* __restrict__ ctl)
{
  int idx = blockIdx.x * 256 + threadIdx.x;
  const int nwc1 = NG * K1, nwc2 = NG * K2, nw2b = 128 * 512, nbi = 2 * NG;
  const int nfh = B * H, nxj = T * B, nctl = 1024;
  if (idx < nwc1) {
    int n = idx / K1, col = idx - n * K1;
    int src = (n & 3) * H + (n >> 2);
    float v = (col < 63) ? Wihc[src * 63 + col]
            : (col == 63 ? 0.f : Whhc[src * 512 + (col - 64)]);
    __hip_bfloat16 h = bhi(v);
    wc1[n * K1 + col] = h; wc1l[n * K1 + col] = blo(v, h);
    return;
  }
  idx -= nwc1;
  if (idx < nwc2) {
    int n = idx / K2, col = idx - n * K2;
    int src = (n & 3) * H + (n >> 2);
    float v;
    if (col < 63)       v = Wihl[src * 575 + col];
    else if (col == 63) v = 0.f;
    else if (col < 576) v = Wihl[src * 575 + (col - 1)];
    else                v = Whhl[src * 512 + (col - 576)];
    __hip_bfloat16 h = bhi(v);
    wc2[n * K2 + col] = h; wc2l[n * K2 + col] = blo(v, h);
    return;
  }
  idx -= nwc2;
  if (idx < nw2b) {
    int n = idx >> 9, col = idx & 511;
    w2b[idx] = bhi(n < OUTW ? W2[n * 512 + col] : 0.f);
    return;
  }
  idx -= nw2b;
  if (idx < nbi) {
    int n = idx & (NG - 1);
    int src = (n & 3) * H + (n >> 2);
    if (idx < NG) bi1[n] = bc[src]; else bi2[n] = bl[src];
    return;
  }
  idx -= nbi;
  if (idx < nfh) {  // slot0 h1 init (hi+lo)
    int b = idx >> 9, j = idx & 511;
    float v = h1h[idx];
    __hip_bfloat16 h = bhi(v);
    fxHL[b * SLOTW + 64 + j] = h;
    fxHL[b * SLOTW + LOOF + 64 + j] = blo(v, h);
    return;
  }
  idx -= nfh;
  if (idx < nfh) {  // slot1 h2 init (hi only)
    int b = idx >> 9, j = idx & 511;
    fxHL[(size_t)SLOTE + b * SLOTW + 576 + j] = bhi(h2h[idx]);
    return;
  }
  idx -= nfh;
  if (idx < nxj) {  // x cols {0,1} hi + lo zeros for slot t+1
    int t = idx >> 7, b = idx & 127;
    float x0 = x[(b * T + t) * 3 + 0], x1 = x[(b * T + t) * 3 + 1];
    unsigned int* ph = (unsigned int*)(fxHL + (size_t)(t + 1) * SLOTE + b * SLOTW);
    ph[0] = pack2(x0, x1);
    unsigned int* pl = (unsigned int*)(fxHL + (size_t)(t + 1) * SLOTE + b * SLOTW + LOOF);
    pl[0] = 0u;
    return;
  }
  idx -= nxj;
  if (idx < nctl) ctl[idx] = 0;
}

DEVFN void store_gsm(int tid, float* Gsm, floatx4 a0, floatx4 a1) {
  const int lane = tid & 63, wv = tid >> 6;
  const int lm = lane & 15, rr = (lane >> 4) << 2;
  #pragma unroll
  for (int r = 0; r < 4; ++r) {
    Gsm[lm * 65 + wv * 16 + rr + r]        = a0[r];
    Gsm[(16 + lm) * 65 + wv * 16 + rr + r] = a1[r];
  }
}

// ---------------- persistent fused kernel ----------------
__global__ __launch_bounds__(256, 1) void k_persist(
    __hip_bfloat16* __restrict__ fxHL,
    const __hip_bfloat16* __restrict__ wc1, const __hip_bfloat16* __restrict__ wc1l,
    const __hip_bfloat16* __restrict__ wc2, const __hip_bfloat16* __restrict__ wc2l,
    const float* __restrict__ bi1, const float* __restrict__ bi2,
    const float* __restrict__ c1init, const float* __restrict__ c2init,
    const float* __restrict__ xin, const float* __restrict__ sent,
    const float* __restrict__ W1, const float* __restrict__ b1,
    int* __restrict__ ctl,
    float* __restrict__ h1f, float* __restrict__ c1f,
    float* __restrict__ h2f, float* __restrict__ c2f)
{
  extern __shared__ char sm[];
  const int gid = blockIdx.x, tid = threadIdx.x;
  const int lane = tid & 63, wv = tid >> 6;
  const int lm = lane & 15, lk = (lane >> 4) << 3;

  if (gid < 128) {
    // ========== G1: window + lstm1 ==========
    const int nt1 = gid >> 1, mh = gid & 1;
    const int n0 = nt1 * 32, m0 = mh * 64;
    const int brow = mh * 64 + nt1;
    int* hf = ctl + mh * 256;            // combined (win+h1) flags, stride FSTR
    __hip_bfloat16* smWh = (__hip_bfloat16*)(sm + O_WH1);
    __hip_bfloat16* smWl = (__hip_bfloat16*)(sm + O_WL1);
    float* smW1 = (float*)(sm + O_W1S);
    float* Gsm  = (float*)(sm + O_GSM);
    float* hs   = (float*)(sm + O_HS);   // aliases Gsm region (window phase only)
    float* winv = (float*)(sm + O_HS);   // reused after hs is dead
    float* pp   = (float*)(sm + O_PP);   // aliases Gsm region (window phase only)
    float* ipl  = (float*)(sm + O_IPL);
    float* kl   = (float*)(sm + O_KL);
    float* phl  = (float*)(sm + O_PHL);
    float* wac  = (float*)(sm + O_WAC);
    float* kpr  = (float*)(sm + O_KPR);
    float* b1s  = (float*)(sm + O_B1S);
    float* bia  = (float*)(sm + O_BIA);
    float* ssent = (float*)(sm + O_SENT);

    for (int i = tid; i < 32 * 72; i += 256) {
      int r = i / 72, c8 = (i - r * 72) * 8;
      *(short8*)(smWh + r * KW1P + c8) = *(const short8*)(wc1  + (size_t)(n0 + r) * K1 + c8);
      *(short8*)(smWl + r * KW1P + c8) = *(const short8*)(wc1l + (size_t)(n0 + r) * K1 + c8);
    }
    for (int i = tid; i < 30 * 512; i += 256) {
      int j = i >> 9, c = i & 511;
      smW1[j * 520 + (c >> 6) * 65 + (c & 63)] = W1[i];
    }
    for (int i = tid; i < 64 * 60; i += 256)
      ssent[i] = sent[(size_t)brow * 64 * 60 + i];   // fp32 — bf16 here fails c1f (R7)
    if (tid < 30) b1s[tid] = b1[tid];
    if (tid < 10) kpr[tid] = 0.f;
    if (tid < 32) bia[tid] = bi1[n0 + tid];
    __syncthreads();

    float creg[2];
    {
      int ml = tid >> 2, ppi = tid & 3;
      creg[0] = c1init[(m0 + ml) * H + nt1 * 8 + 2 * ppi + 0];
      creg[1] = c1init[(m0 + ml) * H + nt1 * 8 + 2 * ppi + 1];
    }

    const __hip_bfloat16* W0h = smWh + lm * KW1P;
    const __hip_bfloat16* W1h = smWh + (16 + lm) * KW1P;
    const __hip_bfloat16* W0l = smWl + lm * KW1P;
    const __hip_bfloat16* W1l = smWl + (16 + lm) * KW1P;

    for (int t = 0; t < T; ++t) {
      __hip_bfloat16* S1 = fxHL + (size_t)(t + 1) * SLOTE;
      __hip_bfloat16* S0 = fxHL + (size_t)t * SLOTE;

      float x2v = xin[(brow * T + t) * 3 + 2];

      // ---- owner-row sentinel poll: h1_{t-1}[brow,:] hi+lo, direct from data ----
      // Starts the window one RT after the data LANDS (no producer drain, no
      // flag store, no flag observe, no separate data load on this path).
      {
        const unsigned int* rb = (const unsigned int*)(S0 + (size_t)brow * SLOTW);
        const unsigned int* hp = rb + 32 + tid;
        const unsigned int* lp = rb + (LOOF >> 1) + 32 + tid;
        unsigned int hw = uald(hp), lw = uald(lp);
        int g = 0;
        while ((hw == SENT || lw == SENT) && g < (1 << 22)) {
          __builtin_amdgcn_s_sleep(1);
          if (hw == SENT) hw = uald(hp);
          if (lw == SENT) lw = uald(lp);
          ++g;
        }
        int c0 = 2 * tid;
        float v0 = bfu((unsigned short)(hw & 0xFFFFu)) + bfu((unsigned short)(lw & 0xFFFFu));
        float v1 = bfu((unsigned short)(hw >> 16)) + bfu((unsigned short)(lw >> 16));
        hs[(c0 >> 6) * 66 + (c0 & 63)] = v0;
        hs[((c0 + 1) >> 6) * 66 + ((c0 + 1) & 63)] = v1;
      }

      // ---- bulk gate: peers' h1 drained (flag), then register A-prefetch ----
      // Flag is usually already set by now (published end of step t-1); loads
      // fly underneath the window compute below.
      waitflags(hf, 64, t);    // internal syncthreads also orders hs writes vs pp reads
      const __hip_bfloat16* Ar = S0 + (size_t)(m0 + wv * 16 + lm) * SLOTW;
      short8 pva[16], pua[16];
      #pragma unroll
      for (int c = 0; c < 16; ++c) {
        pva[c] = *(const short8*)(Ar + (c + 2) * 32 + lk);
        pua[c] = *(const short8*)(Ar + LOOF + (c + 2) * 32 + lk);
      }

      // ---- window compute (LDS only; A-prefetch in flight) ----
      if (tid < 240) {
        int j = tid >> 3, p = tid & 7;
        const float* wp = smW1 + j * 520 + p * 65;
        const float* hv = hs + p * 66;
        float s = 0.f;
        #pragma unroll 8
        for (int k = 0; k < 64; ++k) s += hv[k] * wp[k];
        pp[tid] = s;
      }
      __syncthreads();
      if (tid < 30) {
        float s = b1s[tid];
        #pragma unroll
        for (int p = 0; p < 8; ++p) s += pp[tid * 8 + p];
        ipl[tid] = expf(s);
      }
      __syncthreads();
      if (tid < 10) {
        float kap = ipl[20 + tid] - kpr[tid];
        kpr[tid] = kap; kl[tid] = kap;
      }
      __syncthreads();
      if (tid < 64) {
        float u = (float)(tid + 1);
        float acc = 0.f;
        #pragma unroll
        for (int k = 0; k < 10; ++k) {
          float d = kl[k] - u;
          acc += ipl[k] * expf(-ipl[10 + k] * d * d);
        }
        phl[tid] = acc;
      }
      __syncthreads();
      if (tid < 240) {
        int c = tid >> 2, p = tid & 3;
        float acc = 0.f;
        #pragma unroll
        for (int s0 = 0; s0 < 16; ++s0)
          acc += phl[p * 16 + s0] * ssent[(p * 16 + s0) * 60 + c];
        wac[tid] = acc;
      }
      __syncthreads();
      if (tid < 60)
        winv[tid] = wac[tid * 4] + wac[tid * 4 + 1] + wac[tid * 4 + 2] + wac[tid * 4 + 3];
      __syncthreads();
      if (tid < 31) {  // publish win (dwords 1..31 of hi and lo line-0 region)
        // FIRE-AND-FORGET: no drain, no flag. Consumers sentinel-poll the
        // dwords themselves; G2 is covered by the end-of-step combined flag.
        int d = 1 + tid;
        int c0 = 2 * d, c1 = 2 * d + 1;
        float v0 = (c0 == 2) ? x2v : winv[c0 - 3];
        float v1 = (c1 == 63) ? 0.f : winv[c1 - 3];
        __hip_bfloat16 h0 = bhi(v0), h1v = bhi(v1);
        unsigned int* prow = (unsigned int*)(S1 + (size_t)brow * SLOTW);
        ast(prow + d, (unsigned int)bbits(h0) | ((unsigned int)bbits(h1v) << 16));
        ast(prow + (LOOF >> 1) + d,
            (unsigned int)bbits(blo(v0, h0)) | ((unsigned int)bbits(blo(v1, h1v)) << 16));
      }

      // ---- h-part MFMA from prefetched registers (no global loads) ----
      floatx4 a0 = {0.f, 0.f, 0.f, 0.f}, a1 = a0;
      #pragma unroll
      for (int c = 0; c < 16; ++c) {
        int col = (c + 2) * 32 + lk;
        short8 vb0 = *(const short8*)(W0h + col);
        short8 vb1 = *(const short8*)(W1h + col);
        short8 ub0 = *(const short8*)(W0l + col);
        short8 ub1 = *(const short8*)(W1l + col);
        a0 = __builtin_amdgcn_mfma_f32_16x16x32_bf16(pva[c], vb0, a0, 0, 0, 0);
        a1 = __builtin_amdgcn_mfma_f32_16x16x32_bf16(pva[c], vb1, a1, 0, 0, 0);
        a0 = __builtin_amdgcn_mfma_f32_16x16x32_bf16(pva[c], ub0, a0, 0, 0, 0);
        a1 = __builtin_amdgcn_mfma_f32_16x16x32_bf16(pva[c], ub1, a1, 0, 0, 0);
        a0 = __builtin_amdgcn_mfma_f32_16x16x32_bf16(pua[c], vb0, a0, 0, 0, 0);
        a1 = __builtin_amdgcn_mfma_f32_16x16x32_bf16(pua[c], vb1, a1, 0, 0, 0);
      }

      // ---- win-chunk: sentinel-poll my A-row win dwords, feed MFMA direct ----
      // Replaces waitflags(wf)+gemm3: the polled values ARE the fragments.
      // dword 0 is the x pack (never sentinel) -> polls through instantly.
      {
        const unsigned int* wb = (const unsigned int*)(S1 + (size_t)(m0 + wv * 16 + lm) * SLOTW);
        const int dq = lk >> 1;
        unsigned int d[16];
        #pragma unroll
        for (int c = 0; c < 2; ++c)
          #pragma unroll
          for (int q = 0; q < 4; ++q) {
            d[c * 4 + q]     = uald(wb + c * 16 + dq + q);
            d[8 + c * 4 + q] = uald(wb + (LOOF >> 1) + c * 16 + dq + q);
          }
        int g = 0;
        for (;;) {
          bool any = false;
          #pragma unroll
          for (int j = 0; j < 16; ++j) if (d[j] == SENT) any = true;
          if (!any || g >= (1 << 22)) break;
          __builtin_amdgcn_s_sleep(1);
          #pragma unroll
          for (int c = 0; c < 2; ++c)
            #pragma unroll
            for (int q = 0; q < 4; ++q) {
              if (d[c * 4 + q] == SENT)     d[c * 4 + q]     = uald(wb + c * 16 + dq + q);
              if (d[8 + c * 4 + q] == SENT) d[8 + c * 4 + q] = uald(wb + (LOOF >> 1) + c * 16 + dq + q);
            }
          ++g;
        }
        union U4 { unsigned int u[4]; short8 s; };
        #pragma unroll
        for (int c = 0; c < 2; ++c) {
          U4 va, ua;
          #pragma unroll
          for (int q = 0; q < 4; ++q) { va.u[q] = d[c * 4 + q]; ua.u[q] = d[8 + c * 4 + q]; }
          int col = c * 32 + lk;
          short8 vb0 = *(const short8*)(W0h + col);
          short8 vb1 = *(const short8*)(W1h + col);
          short8 ub0 = *(const short8*)(W0l + col);
          short8 ub1 = *(const short8*)(W1l + col);
          a0 = __builtin_amdgcn_mfma_f32_16x16x32_bf16(va.s, vb0, a0, 0, 0, 0);
          a1 = __builtin_amdgcn_mfma_f32_16x16x32_bf16(va.s, vb1, a1, 0, 0, 0);
          a0 = __builtin_amdgcn_mfma_f32_16x16x32_bf16(va.s, ub0, a0, 0, 0, 0);
          a1 = __builtin_amdgcn_mfma_f32_16x16x32_bf16(va.s, ub1, a1, 0, 0, 0);
          a0 = __builtin_amdgcn_mfma_f32_16x16x32_bf16(ua.s, vb0, a0, 0, 0, 0);
          a1 = __builtin_amdgcn_mfma_f32_16x16x32_bf16(ua.s, vb1, a1, 0, 0, 0);
        }
      }
      store_gsm(tid, Gsm, a0, a1);
      __syncthreads();

      // ---- epilogue: each thread 2 adjacent h-cols of one m-row ----
      {
        int ml = tid >> 2, ppi = tid & 3;
        float v[2];
        #pragma unroll
        for (int j = 0; j < 2; ++j) {
          int nl = ppi * 8 + j * 4;
          float gi = Gsm[(nl + 0) * 65 + ml] + bia[nl + 0];
          float gf = Gsm[(nl + 1) * 65 + ml] + bia[nl + 1];
          float gg = Gsm[(nl + 2) * 65 + ml] + bia[nl + 2];
          float go = Gsm[(nl + 3) * 65 + ml] + bia[nl + 3];
          float ig = 1.f / (1.f + expf(-gi));
          float fg = 1.f / (1.f + expf(-gf));
          float gt = tanhf(gg);
          float og = 1.f / (1.f + expf(-go));
          float cn = fg * creg[j] + ig * gt;
          v[j] = og * tanhf(cn);
          creg[j] = cn;
        }
        __hip_bfloat16 h0 = bhi(v[0]), h1v = bhi(v[1]);
        unsigned int* prow = (unsigned int*)(S1 + (size_t)(m0 + ml) * SLOTW);
        int dw = 32 + nt1 * 4 + ppi;       // hi dword of cols {64+nt1*8+2p, +1}
        ast(prow + dw, (unsigned int)bbits(h0) | ((unsigned int)bbits(h1v) << 16));
        ast(prow + (LOOF >> 1) + dw,
            (unsigned int)bbits(blo(v[0], h0)) | ((unsigned int)bbits(blo(v[1], h1v)) << 16));
        if (t == T - 1) {
          int hg = nt1 * 8 + 2 * ppi;
          h1f[(m0 + ml) * H + hg]     = v[0];  c1f[(m0 + ml) * H + hg]     = creg[0];
          h1f[(m0 + ml) * H + hg + 1] = v[1];  c1f[(m0 + ml) * H + hg + 1] = creg[1];
        }
      }
      // combined flag: drains win_t (fired earlier, wave 0) AND h1_t stores
      flag_store(hf + nt1 * FSTR, t + 1);
    }
  } else {
    // ========== G2: lstm2 ==========
    const int g2 = gid - 128;
    const int nt2 = g2 >> 1, mh = g2 & 1;
    const int n0 = nt2 * 32, m0 = mh * 64;
    int* hf  = ctl + mh * 256;             // combined (win+h1) flags
    int* h2g = ctl + 512 + mh * 256;       // h2 flags
    __hip_bfloat16* smWh = (__hip_bfloat16*)(sm + O_WH2);
    __hip_bfloat16* smWl = (__hip_bfloat16*)(sm + O_WL2);
    float* Gsm = (float*)(sm + O_GS2);
    float* bia = (float*)(sm + O_BI2);

    for (int i = tid; i < 32 * 136; i += 256) {
      int r = i / 136, c8 = (i - r * 136) * 8;
      *(short8*)(smWh + r * KW2P + c8) = *(const short8*)(wc2  + (size_t)(n0 + r) * K2 + c8);
      *(short8*)(smWl + r * KW2P + c8) = *(const short8*)(wc2l + (size_t)(n0 + r) * K2 + c8);
    }
    if (tid < 32) bia[tid] = bi2[n0 + tid];
    __syncthreads();

    float creg[2];
    {
      int ml = tid >> 2, ppi = tid & 3;
      creg[0] = c2init[(m0 + ml) * H + nt2 * 8 + 2 * ppi + 0];
      creg[1] = c2init[(m0 + ml) * H + nt2 * 8 + 2 * ppi + 1];
    }

    const __hip_bfloat16* W0h = smWh + lm * KW2P;
    const __hip_bfloat16* W1h = smWh + (16 + lm) * KW2P;
    const __hip_bfloat16* W0l = smWl + lm * KW2P;
    const __hip_bfloat16* W1l = smWl + (16 + lm) * KW2P;

    for (int t = 0; t < T; ++t) {
      __hip_bfloat16* S1 = fxHL + (size_t)(t + 1) * SLOTE;
      __hip_bfloat16* S2 = fxHL + (size_t)(t + 2) * SLOTE;
      const __hip_bfloat16* Ar = S1 + (size_t)(m0 + wv * 16 + lm) * SLOTW;

      // own-half h2_{t-1} complete in S1 -> prefetch h2-part A (hi only)
      waitflags(h2g, 64, t);
      short8 pv2[16];
      #pragma unroll
      for (int c = 0; c < 16; ++c)
        pv2[c] = *(const short8*)(Ar + (K1C + c) * 32 + lk);
      floatx4 a0 = {0.f, 0.f, 0.f, 0.f}, a1 = a0;
      #pragma unroll
      for (int c = 0; c < 16; ++c) {
        int col = (K1C + c) * 32 + lk;
        short8 vb0 = *(const short8*)(W0h + col);
        short8 vb1 = *(const short8*)(W1h + col);
        short8 ub0 = *(const short8*)(W0l + col);
        short8 ub1 = *(const short8*)(W1l + col);
        a0 = __builtin_amdgcn_mfma_f32_16x16x32_bf16(pv2[c], vb0, a0, 0, 0, 0);
        a1 = __builtin_amdgcn_mfma_f32_16x16x32_bf16(pv2[c], vb1, a1, 0, 0, 0);
        a0 = __builtin_amdgcn_mfma_f32_16x16x32_bf16(pv2[c], ub0, a0, 0, 0, 0);
        a1 = __builtin_amdgcn_mfma_f32_16x16x32_bf16(pv2[c], ub1, a1, 0, 0, 0);
      }
      // win_t and h1_t in S1: combined flag covers both (win fired before the
      // G1 epilogue; the G1 end-of-step vmcnt(0) drains win+h together)
      waitflags(hf, 64, t + 1);
      short8 qv[18], qu[18];
      #pragma unroll
      for (int c = 0; c < 18; ++c) {
        qv[c] = *(const short8*)(Ar + c * 32 + lk);
        qu[c] = *(const short8*)(Ar + LOOF + c * 32 + lk);
      }
      #pragma unroll
      for (int c = 0; c < 18; ++c) {
        int col = c * 32 + lk;
        short8 vb0 = *(const short8*)(W0h + col);
        short8 vb1 = *(const short8*)(W1h + col);
        short8 ub0 = *(const short8*)(W0l + col);
        short8 ub1 = *(const short8*)(W1l + col);
        a0 = __builtin_amdgcn_mfma_f32_16x16x32_bf16(qv[c], vb0, a0, 0, 0, 0);
        a1 = __builtin_amdgcn_mfma_f32_16x16x32_bf16(qv[c], vb1, a1, 0, 0, 0);
        a0 = __builtin_amdgcn_mfma_f32_16x16x32_bf16(qv[c], ub0, a0, 0, 0, 0);
        a1 = __builtin_amdgcn_mfma_f32_16x16x32_bf16(qv[c], ub1, a1, 0, 0, 0);
        a0 = __builtin_amdgcn_mfma_f32_16x16x32_bf16(qu[c], vb0, a0, 0, 0, 0);
        a1 = __builtin_amdgcn_mfma_f32_16x16x32_bf16(qu[c], vb1, a1, 0, 0, 0);
      }
      store_gsm(tid, Gsm, a0, a1);
      __syncthreads();

      {
        int ml = tid >> 2, ppi = tid & 3;
        float v[2];
        #pragma unroll
        for (int j = 0; j < 2; ++j) {
          int nl = ppi * 8 + j * 4;
          float gi = Gsm[(nl + 0) * 65 + ml] + bia[nl + 0];
          float gf = Gsm[(nl + 1) * 65 + ml] + bia[nl + 1];
          float gg = Gsm[(nl + 2) * 65 + ml] + bia[nl + 2];
          float go = Gsm[(nl + 3) * 65 + ml] + bia[nl + 3];
          float ig = 1.f / (1.f + expf(-gi));
          float fg = 1.f / (1.f + expf(-gf));
          float gt = tanhf(gg);
          float og = 1.f / (1.f + expf(-go));
          float cn = fg * creg[j] + ig * gt;
          v[j] = og * tanhf(cn);
          creg[j] = cn;
        }
        __hip_bfloat16 h0 = bhi(v[0]), h1v = bhi(v[1]);
        unsigned int* prow = (unsigned int*)(S2 + (size_t)(m0 + ml) * SLOTW);
        int dw = 288 + nt2 * 4 + ppi;      // hi dword of cols {576+nt2*8+2p, +1}
        ast(prow + dw, (unsigned int)bbits(h0) | ((unsigned int)bbits(h1v) << 16));
        if (t == T - 1) {
          int hg = nt2 * 8 + 2 * ppi;
          h2f[(m0 + ml) * H + hg]     = v[0];  c2f[(m0 + ml) * H + hg]     = creg[0];
          h2f[(m0 + ml) * H + hg + 1] = v[1];  c2f[(m0 + ml) * H + hg + 1] = creg[1];
        }
      }
      flag_store(h2g + nt2 * FSTR, t + 1);     // h2 slice published
    }
  }
}

// ---------------- final GEMM: out[BT x 121] = h2 @ W2^T + b2 ----------------
__global__ __launch_bounds__(256) void k_out(
    const __hip_bfloat16* __restrict__ fxHL, const __hip_bfloat16* __restrict__ w2b,
    const float* __restrict__ b2, float* __restrict__ dout)
{
  int bid = blockIdx.x, tid = threadIdx.x;
  int mblk = bid >> 1, nblk = bid & 1;
  int wv = tid >> 6, lane = tid & 63;
  int lm = lane & 15, lk = (lane >> 4) << 3;
  int m0 = mblk * 128 + wv * 32;
  int n0 = nblk * 64;
  int r0 = m0 + lm, r1 = m0 + 16 + lm;
  const __hip_bfloat16* a0p = fxHL + (size_t)((r0 & 255) + 2) * SLOTE + (r0 >> 8) * SLOTW + 576;
  const __hip_bfloat16* a1p = fxHL + (size_t)((r1 & 255) + 2) * SLOTE + (r1 >> 8) * SLOTW + 576;
  floatx4 zz = {0.f, 0.f, 0.f, 0.f};
  floatx4 acc[2][4];
  #pragma unroll
  for (int mt = 0; mt < 2; ++mt)
    #pragma unroll
    for (int nt = 0; nt < 4; ++nt) acc[mt][nt] = zz;
  #pragma unroll
  for (int c = 0; c < 16; ++c) {
    int col = c * 32 + lk;
    short8 va0 = *(const short8*)(a0p + col);
    short8 va1 = *(const short8*)(a1p + col);
    short8 vb[4];
    #pragma unroll
    for (int nt = 0; nt < 4; ++nt)
      vb[nt] = *(const short8*)(w2b + (size_t)(n0 + nt * 16 + lm) * 512 + col);
    #pragma unroll
    for (int nt = 0; nt < 4; ++nt) {
      acc[0][nt] = __builtin_amdgcn_mfma_f32_16x16x32_bf16(va0, vb[nt], acc[0][nt], 0, 0, 0);
      acc[1][nt] = __builtin_amdgcn_mfma_f32_16x16x32_bf16(va1, vb[nt], acc[1][nt], 0, 0, 0);
    }
  }
  int rr = (lane >> 4) << 2;
  #pragma unroll
  for (int mt = 0; mt < 2; ++mt)
    #pragma unroll
    for (int nt = 0; nt < 4; ++nt)
      #pragma unroll
      for (int r = 0; r < 4; ++r) {
        int m = m0 + mt * 16 + rr + r;
        int n = n0 + nt * 16 + lm;
        if (n < OUTW) dout[(size_t)m * OUTW + n] = acc[mt][nt][r] + b2[n];
      }
}

// ---------------- host ----------------
extern "C" void kernel_launch(void* const* d_in, const int* in_sizes, int n_in,
                              void* d_out, int out_size, void* d_ws, size_t ws_size,
                              hipStream_t stream)
{
  (void)in_sizes; (void)n_in; (void)out_size; (void)ws_size;
  const float* x    = (const float*)d_in[0];
  const float* sent = (const float*)d_in[1];
  const float* h1h  = (const float*)d_in[2];
  const float* h1c  = (const float*)d_in[3];
  const float* h2h  = (const float*)d_in[4];
  const float* h2c  = (const float*)d_in[5];
  const float* Wihc = (const float*)d_in[6];
  const float* Whhc = (const float*)d_in[7];
  const float* bc   = (const float*)d_in[8];
  const float* Wihl = (const float*)d_in[9];
  const float* Whhl = (const float*)d_in[10];
  const float* bl   = (const float*)d_in[11];
  const float* W1   = (const float*)d_in[12];
  const float* b1   = (const float*)d_in[13];
  const float* W2   = (const float*)d_in[14];
  const float* b2   = (const float*)d_in[15];

  float* out = (float*)d_out;
  float* h1f = out + (size_t)B * T * OUTW;
  float* c1f = h1f + (size_t)B * H;
  float* h2f = c1f + (size_t)B * H;
  float* c2f = h2f + (size_t)B * H;

  char* p = (char*)d_ws;
  auto carve = [&](size_t bytes) { char* r = p; p += (bytes + 255) & ~(size_t)255; return r; };
  __hip_bfloat16* fxHL = (__hip_bfloat16*)carve((size_t)NSLOT * SLOTE * 2);
  __hip_bfloat16* wc1  = (__hip_bfloat16*)carve((size_t)NG * K1 * 2);
  __hip_bfloat16* wc1l = (__hip_bfloat16*)carve((size_t)NG * K1 * 2);
  __hip_bfloat16* wc2  = (__hip_bfloat16*)carve((size_t)NG * K2 * 2);
  __hip_bfloat16* wc2l = (__hip_bfloat16*)carve((size_t)NG * K2 * 2);
  __hip_bfloat16* w2b  = (__hip_bfloat16*)carve((size_t)128 * 512 * 2);
  float* bi1 = (float*)carve((size_t)NG * 4);
  float* bi2 = (float*)carve((size_t)NG * 4);
  int*   ctl = (int*)carve((size_t)1024 * 4);

  static bool attr_set = false;
  if (!attr_set) {
    (void)hipFuncSetAttribute((const void*)k_persist,
                              hipFuncAttributeMaxDynamicSharedMemorySize, LDS_SZ);
    attr_set = true;
  }

  k_sent<<<32768, 256, 0, stream>>>(fxHL);
  k_pre<<<14228, 256, 0, stream>>>(x, h1h, h2h, Wihc, Whhc, bc, Wihl, Whhl, bl, W2,
                                   fxHL, wc1, wc1l, wc2, wc2l, w2b, bi1, bi2, ctl);
  k_persist<<<256, 256, LDS_SZ, stream>>>(fxHL, wc1, wc1l, wc2, wc2l, bi1, bi2,
                                          h1c, h2c, x, sent, W1, b1, ctl,
                                          h1f, c1f, h2f, c2f);
  k_out<<<512, 256, 0, stream>>>(fxHL, w2b, b2, out);
}

// Round 2
// 2683.973 us; speedup vs baseline: 1.1052x; 1.0782x over previous
//
#include <hip/hip_runtime.h>
#include <hip/hip_bf16.h>
#include <math.h>

typedef __attribute__((ext_vector_type(8))) short short8;
typedef __attribute__((ext_vector_type(4))) float floatx4;

#define DEVFN static __device__ __forceinline__

constexpr int B = 128, T = 256, H = 512;
constexpr int OUTW = 121;
// fxHL slot row layout (per batch row, per time slot), elems:
//   hi: [x(3) win(60) pad(1) h1(512) h2(512)] = 1088
//   lo: cols 0..575 only (x,win,h1)           = 576
constexpr int SLOTW = 1664;              // row stride in elems (hi 1088 + lo 576)
constexpr int LOOF  = 1088;              // lo region offset within row
constexpr int SLOTE = B * SLOTW;         // elems per time slot
constexpr int NSLOT = T + 2;
constexpr int NG  = 2048;                // 4*H gate rows (interleaved n' = hcol*4+gate)
constexpr int K1  = 576,  K1C = 18;
constexpr int K2  = 1088, K2C = 34;
constexpr int KW1P = 584, KW2P = 1096;   // LDS weight row pads

// ---- LDS offsets (bytes) ----
// G1 path. NOTE: hs/pp alias the Gsm region — window phase and GEMM phase are
// temporally disjoint (separated by barriers), verified in-source below.
constexpr int O_WH1 = 0;                 // 32*584*2 = 37376
constexpr int O_WL1 = 37376;             // -> 74752
constexpr int O_W1S = 74752;             // 30*520*4 = 62400 -> 137152
constexpr int O_GSM = 137152;            // 32*65*4 = 8320 -> 145472
constexpr int O_HS  = 137152;            // 528*4 = 2112 (alias in Gsm; also winv)
constexpr int O_PP  = 139264;            // 240*4 = 960 (alias in Gsm)
constexpr int O_IPL = 145472;            // 30*4
constexpr int O_KL  = 145592;            // 10*4
constexpr int O_PHL = 145632;            // 64*4
constexpr int O_WAC = 145888;            // 240*4
constexpr int O_KPR = 146848;            // 10*4
constexpr int O_B1S = 146888;            // 30*4
constexpr int O_BIA = 147008;            // 32*4 -> 147136
constexpr int O_SENT = 147136;           // 64*60 fp32 = 15360 -> 162496
// G2 path:
constexpr int O_WH2 = 0;                 // 32*1096*2 = 70144
constexpr int O_WL2 = 70144;             // -> 140288
constexpr int O_GS2 = 140288;            // 8320 -> 148608
constexpr int O_BI2 = 148608;            // 128 -> 148736
constexpr int LDS_SZ = 162496;

DEVFN __hip_bfloat16 bhi(float v) { return __float2bfloat16(v); }
DEVFN __hip_bfloat16 blo(float v, __hip_bfloat16 h) { return __float2bfloat16(v - __bfloat162float(h)); }
DEVFN float bf2f(__hip_bfloat16 h) { return __bfloat162float(h); }
DEVFN unsigned short bbits(__hip_bfloat16 h) { union { __hip_bfloat16 h; unsigned short u; } c; c.h = h; return c.u; }
DEVFN unsigned int pack2(float a, float b) {
  return (unsigned int)bbits(bhi(a)) | ((unsigned int)bbits(bhi(b)) << 16);
}
DEVFN void ast(unsigned int* p, unsigned int v) {
  __hip_atomic_store(p, v, __ATOMIC_RELAXED, __HIP_MEMORY_SCOPE_AGENT);
}
DEVFN int ald(int* p) {
  return __hip_atomic_load(p, __ATOMIC_RELAXED, __HIP_MEMORY_SCOPE_AGENT);
}

// ---- single-counter barriers ----
// Consumer: ONE thread polls ONE dword, barrier releases the block.
// (Replaces 64-flag waits: a flag array polled by 64-256 threads x 256 blocks
// with cache-bypassing loads was a contention storm on a few lines.)
DEVFN void waitcnt_ge(int* cnt, int target) {
  if (threadIdx.x == 0) {
    int g = 0;
    while (ald(cnt) < target && g < (1 << 24)) { ++g; __builtin_amdgcn_s_sleep(1); }
  }
  asm volatile("" ::: "memory");
  __syncthreads();
}
// Producer: drain own stores (all waves), then one atomic increment.
DEVFN void cnt_add(int* cnt) {
  asm volatile("s_waitcnt vmcnt(0)" ::: "memory");
  __syncthreads();
  if (threadIdx.x == 0)
    (void)__hip_atomic_fetch_add(cnt, 1, __ATOMIC_RELAXED, __HIP_MEMORY_SCOPE_AGENT);
}

// ---------------- precompute ----------------
__global__ __launch_bounds__(256) void k_pre(
    const float* __restrict__ x, const float* __restrict__ h1h, const float* __restrict__ h2h,
    const float* __restrict__ Wihc, const float* __restrict__ Whhc, const float* __restrict__ bc,
    const float* __restrict__ Wihl, const float* __restrict__ Whhl, const float* __restrict__ bl,
    const float* __restrict__ W2,
    __hip_bfloat16* __restrict__ fxHL,
    __hip_bfloat16* __restrict__ wc1, __hip_bfloat16* __restrict__ wc1l,
    __hip_bfloat16* __restrict__ wc2, __hip_bfloat16* __restrict__ wc2l,
    __hip_bfloat16* __restrict__ w2b, float* __restrict__ bi1, float* __restrict__ bi2,
    int* __restrict__ ctl)
{
  int idx = blockIdx.x * 256 + threadIdx.x;
  const int nwc1 = NG * K1, nwc2 = NG * K2, nw2b = 128 * 512, nbi = 2 * NG;
  const int nfh = B * H, nxj = T * B, nctl = 512;
  if (idx < nwc1) {
    int n = idx / K1, col = idx - n * K1;
    int src = (n & 3) * H + (n >> 2);
    float v = (col < 63) ? Wihc[src * 63 + col]
            : (col == 63 ? 0.f : Whhc[src * 512 + (col - 64)]);
    __hip_bfloat16 h = bhi(v);
    wc1[n * K1 + col] = h; wc1l[n * K1 + col] = blo(v, h);
    return;
  }
  idx -= nwc1;
  if (idx < nwc2) {
    int n = idx / K2, col = idx - n * K2;
    int src = (n & 3) * H + (n >> 2);
    float v;
    if (col < 63)       v = Wihl[src * 575 + col];
    else if (col == 63) v = 0.f;
    else if (col < 576) v = Wihl[src * 575 + (col - 1)];
    else                v = Whhl[src * 512 + (col - 576)];
    __hip_bfloat16 h = bhi(v);
    wc2[n * K2 + col] = h; wc2l[n * K2 + col] = blo(v, h);
    return;
  }
  idx -= nwc2;
  if (idx < nw2b) {
    int n = idx >> 9, col = idx & 511;
    w2b[idx] = bhi(n < OUTW ? W2[n * 512 + col] : 0.f);
    return;
  }
  idx -= nw2b;
  if (idx < nbi) {
    int n = idx & (NG - 1);
    int src = (n & 3) * H + (n >> 2);
    if (idx < NG) bi1[n] = bc[src]; else bi2[n] = bl[src];
    return;
  }
  idx -= nbi;
  if (idx < nfh) {  // slot0 h1 init (hi+lo)
    int b = idx >> 9, j = idx & 511;
    float v = h1h[idx];
    __hip_bfloat16 h = bhi(v);
    fxHL[b * SLOTW + 64 + j] = h;
    fxHL[b * SLOTW + LOOF + 64 + j] = blo(v, h);
    return;
  }
  idx -= nfh;
  if (idx < nfh) {  // slot1 h2 init (hi only)
    int b = idx >> 9, j = idx & 511;
    fxHL[(size_t)SLOTE + b * SLOTW + 576 + j] = bhi(h2h[idx]);
    return;
  }
  idx -= nfh;
  if (idx < nxj) {  // x cols {0,1} hi + lo zeros for slot t+1
    int t = idx >> 7, b = idx & 127;
    float x0 = x[(b * T + t) * 3 + 0], x1 = x[(b * T + t) * 3 + 1];
    unsigned int* ph = (unsigned int*)(fxHL + (size_t)(t + 1) * SLOTE + b * SLOTW);
    ph[0] = pack2(x0, x1);
    unsigned int* pl = (unsigned int*)(fxHL + (size_t)(t + 1) * SLOTE + b * SLOTW + LOOF);
    pl[0] = 0u;
    return;
  }
  idx -= nxj;
  if (idx < nctl) ctl[idx] = 0;
}

// ---------------- MFMA helper (A rows from global, W in LDS) ----------------
template <int KWP>
DEVFN void gemm3(int tid, const __hip_bfloat16* __restrict__ Aslot, int m0,
                 const __hip_bfloat16* __restrict__ Wh, const __hip_bfloat16* __restrict__ Wl,
                 int cbeg, int cend, floatx4& a0, floatx4& a1)
{
  const int lane = tid & 63, wv = tid >> 6;
  const int lm = lane & 15, lk = (lane >> 4) << 3;
  const __hip_bfloat16* Ar = Aslot + (size_t)(m0 + wv * 16 + lm) * SLOTW;
  const __hip_bfloat16* W0h = Wh + lm * KWP;
  const __hip_bfloat16* W1h = Wh + (16 + lm) * KWP;
  const __hip_bfloat16* W0l = Wl + lm * KWP;
  const __hip_bfloat16* W1l = Wl + (16 + lm) * KWP;
  #pragma unroll 4
  for (int c = cbeg; c < cend; ++c) {
    int col = c * 32 + lk;
    short8 va  = *(const short8*)(Ar + col);
    short8 ua  = *(const short8*)(Ar + LOOF + col);
    short8 vb0 = *(const short8*)(W0h + col);
    short8 vb1 = *(const short8*)(W1h + col);
    short8 ub0 = *(const short8*)(W0l + col);
    short8 ub1 = *(const short8*)(W1l + col);
    a0 = __builtin_amdgcn_mfma_f32_16x16x32_bf16(va, vb0, a0, 0, 0, 0);
    a1 = __builtin_amdgcn_mfma_f32_16x16x32_bf16(va, vb1, a1, 0, 0, 0);
    a0 = __builtin_amdgcn_mfma_f32_16x16x32_bf16(va, ub0, a0, 0, 0, 0);
    a1 = __builtin_amdgcn_mfma_f32_16x16x32_bf16(va, ub1, a1, 0, 0, 0);
    a0 = __builtin_amdgcn_mfma_f32_16x16x32_bf16(ua, vb0, a0, 0, 0, 0);
    a1 = __builtin_amdgcn_mfma_f32_16x16x32_bf16(ua, vb1, a1, 0, 0, 0);
  }
}

DEVFN void store_gsm(int tid, float* Gsm, floatx4 a0, floatx4 a1) {
  const int lane = tid & 63, wv = tid >> 6;
  const int lm = lane & 15, rr = (lane >> 4) << 2;
  #pragma unroll
  for (int r = 0; r < 4; ++r) {
    Gsm[lm * 65 + wv * 16 + rr + r]        = a0[r];
    Gsm[(16 + lm) * 65 + wv * 16 + rr + r] = a1[r];
  }
}

// ---------------- persistent fused kernel ----------------
__global__ __launch_bounds__(256, 1) void k_persist(
    __hip_bfloat16* __restrict__ fxHL,
    const __hip_bfloat16* __restrict__ wc1, const __hip_bfloat16* __restrict__ wc1l,
    const __hip_bfloat16* __restrict__ wc2, const __hip_bfloat16* __restrict__ wc2l,
    const float* __restrict__ bi1, const float* __restrict__ bi2,
    const float* __restrict__ c1init, const float* __restrict__ c2init,
    const float* __restrict__ xin, const float* __restrict__ sent,
    const float* __restrict__ W1, const float* __restrict__ b1,
    int* __restrict__ ctl,
    float* __restrict__ h1f, float* __restrict__ c1f,
    float* __restrict__ h2f, float* __restrict__ c2f)
{
  extern __shared__ char sm[];
  const int gid = blockIdx.x, tid = threadIdx.x;
  const int lane = tid & 63, wv = tid >> 6;
  const int lm = lane & 15, lk = (lane >> 4) << 3;

  if (gid < 128) {
    // ========== G1: window + lstm1 ==========
    const int nt1 = gid >> 1, mh = gid & 1;
    const int n0 = nt1 * 32, m0 = mh * 64;
    const int brow = mh * 64 + nt1;
    // counters: each on its own 128B line
    int* hcnt = ctl + mh * 32;           // h1 step completion (covers win too)
    int* wcnt = ctl + 64 + mh * 32;      // win publication (mid-step)
    __hip_bfloat16* smWh = (__hip_bfloat16*)(sm + O_WH1);
    __hip_bfloat16* smWl = (__hip_bfloat16*)(sm + O_WL1);
    float* smW1 = (float*)(sm + O_W1S);
    float* Gsm  = (float*)(sm + O_GSM);
    float* hs   = (float*)(sm + O_HS);   // aliases Gsm region (window phase only)
    float* winv = (float*)(sm + O_HS);   // reused after hs is dead
    float* pp   = (float*)(sm + O_PP);   // aliases Gsm region (window phase only)
    float* ipl  = (float*)(sm + O_IPL);
    float* kl   = (float*)(sm + O_KL);
    float* phl  = (float*)(sm + O_PHL);
    float* wac  = (float*)(sm + O_WAC);
    float* kpr  = (float*)(sm + O_KPR);
    float* b1s  = (float*)(sm + O_B1S);
    float* bia  = (float*)(sm + O_BIA);
    float* ssent = (float*)(sm + O_SENT);

    for (int i = tid; i < 32 * 72; i += 256) {
      int r = i / 72, c8 = (i - r * 72) * 8;
      *(short8*)(smWh + r * KW1P + c8) = *(const short8*)(wc1  + (size_t)(n0 + r) * K1 + c8);
      *(short8*)(smWl + r * KW1P + c8) = *(const short8*)(wc1l + (size_t)(n0 + r) * K1 + c8);
    }
    for (int i = tid; i < 30 * 512; i += 256) {
      int j = i >> 9, c = i & 511;
      smW1[j * 520 + (c >> 6) * 65 + (c & 63)] = W1[i];
    }
    for (int i = tid; i < 64 * 60; i += 256)
      ssent[i] = sent[(size_t)brow * 64 * 60 + i];   // fp32 — bf16 here fails c1f (R7)
    if (tid < 30) b1s[tid] = b1[tid];
    if (tid < 10) kpr[tid] = 0.f;
    if (tid < 32) bia[tid] = bi1[n0 + tid];
    __syncthreads();

    float creg[2];
    {
      int ml = tid >> 2, ppi = tid & 3;
      creg[0] = c1init[(m0 + ml) * H + nt1 * 8 + 2 * ppi + 0];
      creg[1] = c1init[(m0 + ml) * H + nt1 * 8 + 2 * ppi + 1];
    }

    const __hip_bfloat16* W0h = smWh + lm * KW1P;
    const __hip_bfloat16* W1h = smWh + (16 + lm) * KW1P;
    const __hip_bfloat16* W0l = smWl + lm * KW1P;
    const __hip_bfloat16* W1l = smWl + (16 + lm) * KW1P;

    for (int t = 0; t < T; ++t) {
      __hip_bfloat16* S1 = fxHL + (size_t)(t + 1) * SLOTE;
      __hip_bfloat16* S0 = fxHL + (size_t)t * SLOTE;

      waitcnt_ge(hcnt, 64 * t);   // all same-half h1_{t-1} published

      // ---- issue window h1-row loads, x scalar, then register A-prefetch ----
      const __hip_bfloat16* wrow = S0 + (size_t)brow * SLOTW;
      __hip_bfloat16 a0h = wrow[64 + tid];
      __hip_bfloat16 a0l = wrow[LOOF + 64 + tid];
      __hip_bfloat16 a1h = wrow[64 + 256 + tid];
      __hip_bfloat16 a1l = wrow[LOOF + 64 + 256 + tid];
      float x2v = xin[(brow * T + t) * 3 + 2];
      const __hip_bfloat16* Ar = S0 + (size_t)(m0 + wv * 16 + lm) * SLOTW;
      short8 pva[16], pua[16];
      #pragma unroll
      for (int c = 0; c < 16; ++c) {
        pva[c] = *(const short8*)(Ar + (c + 2) * 32 + lk);
        pua[c] = *(const short8*)(Ar + LOOF + (c + 2) * 32 + lk);
      }
      hs[(tid >> 6) * 66 + (tid & 63)] = bf2f(a0h) + bf2f(a0l);
      hs[((tid + 256) >> 6) * 66 + (tid & 63)] = bf2f(a1h) + bf2f(a1l);
      __syncthreads();

      // ---- window compute (LDS only; overlaps A-prefetch in flight) ----
      if (tid < 240) {
        int j = tid >> 3, p = tid & 7;
        const float* wp = smW1 + j * 520 + p * 65;
        const float* hv = hs + p * 66;
        float s = 0.f;
        #pragma unroll 8
        for (int k = 0; k < 64; ++k) s += hv[k] * wp[k];
        pp[tid] = s;
      }
      __syncthreads();
      if (tid < 30) {
        float s = b1s[tid];
        #pragma unroll
        for (int p = 0; p < 8; ++p) s += pp[tid * 8 + p];
        ipl[tid] = expf(s);
      }
      __syncthreads();
      if (tid < 10) {
        float kap = ipl[20 + tid] - kpr[tid];
        kpr[tid] = kap; kl[tid] = kap;
      }
      __syncthreads();
      if (tid < 64) {
        float u = (float)(tid + 1);
        float acc = 0.f;
        #pragma unroll
        for (int k = 0; k < 10; ++k) {
          float d = kl[k] - u;
          acc += ipl[k] * expf(-ipl[10 + k] * d * d);
        }
        phl[tid] = acc;
      }
      __syncthreads();
      if (tid < 240) {
        int c = tid >> 2, p = tid & 3;
        float acc = 0.f;
        #pragma unroll
        for (int s0 = 0; s0 < 16; ++s0)
          acc += phl[p * 16 + s0] * ssent[(p * 16 + s0) * 60 + c];
        wac[tid] = acc;
      }
      __syncthreads();
      if (tid < 60)
        winv[tid] = wac[tid * 4] + wac[tid * 4 + 1] + wac[tid * 4 + 2] + wac[tid * 4 + 3];
      __syncthreads();
      if (tid < 31) {  // publish win (dwords 1..31 of hi and lo line-0 region)
        int d = 1 + tid;
        int c0 = 2 * d, c1 = 2 * d + 1;
        float v0 = (c0 == 2) ? x2v : winv[c0 - 3];
        float v1 = (c1 == 63) ? 0.f : winv[c1 - 3];
        __hip_bfloat16 h0 = bhi(v0), h1v = bhi(v1);
        unsigned int* prow = (unsigned int*)(S1 + (size_t)brow * SLOTW);
        ast(prow + d, (unsigned int)bbits(h0) | ((unsigned int)bbits(h1v) << 16));
        ast(prow + (LOOF >> 1) + d,
            (unsigned int)bbits(blo(v0, h0)) | ((unsigned int)bbits(blo(v1, h1v)) << 16));
      }
      cnt_add(wcnt);                        // win(brow) published

      // ---- h1-part MFMA from prefetched registers (no global loads) ----
      floatx4 a0 = {0.f, 0.f, 0.f, 0.f}, a1 = a0;
      #pragma unroll
      for (int c = 0; c < 16; ++c) {
        int col = (c + 2) * 32 + lk;
        short8 vb0 = *(const short8*)(W0h + col);
        short8 vb1 = *(const short8*)(W1h + col);
        short8 ub0 = *(const short8*)(W0l + col);
        short8 ub1 = *(const short8*)(W1l + col);
        a0 = __builtin_amdgcn_mfma_f32_16x16x32_bf16(pva[c], vb0, a0, 0, 0, 0);
        a1 = __builtin_amdgcn_mfma_f32_16x16x32_bf16(pva[c], vb1, a1, 0, 0, 0);
        a0 = __builtin_amdgcn_mfma_f32_16x16x32_bf16(pva[c], ub0, a0, 0, 0, 0);
        a1 = __builtin_amdgcn_mfma_f32_16x16x32_bf16(pva[c], ub1, a1, 0, 0, 0);
        a0 = __builtin_amdgcn_mfma_f32_16x16x32_bf16(pua[c], vb0, a0, 0, 0, 0);
        a1 = __builtin_amdgcn_mfma_f32_16x16x32_bf16(pua[c], vb1, a1, 0, 0, 0);
      }
      waitcnt_ge(wcnt, 64 * (t + 1));       // all wins of this half available
      gemm3<KW1P>(tid, S1, m0, smWh, smWl, 0, 2, a0, a1);
      store_gsm(tid, Gsm, a0, a1);
      __syncthreads();

      // ---- epilogue: each thread 2 adjacent h-cols of one m-row ----
      {
        int ml = tid >> 2, ppi = tid & 3;
        float v[2];
        #pragma unroll
        for (int j = 0; j < 2; ++j) {
          int nl = ppi * 8 + j * 4;
          float gi = Gsm[(nl + 0) * 65 + ml] + bia[nl + 0];
          float gf = Gsm[(nl + 1) * 65 + ml] + bia[nl + 1];
          float gg = Gsm[(nl + 2) * 65 + ml] + bia[nl + 2];
          float go = Gsm[(nl + 3) * 65 + ml] + bia[nl + 3];
          float ig = 1.f / (1.f + expf(-gi));
          float fg = 1.f / (1.f + expf(-gf));
          float gt = tanhf(gg);
          float og = 1.f / (1.f + expf(-go));
          float cn = fg * creg[j] + ig * gt;
          v[j] = og * tanhf(cn);
          creg[j] = cn;
        }
        __hip_bfloat16 h0 = bhi(v[0]), h1v = bhi(v[1]);
        unsigned int* prow = (unsigned int*)(S1 + (size_t)(m0 + ml) * SLOTW);
        int dw = 32 + nt1 * 4 + ppi;       // hi dword of cols {64+nt1*8+2p, +1}
        ast(prow + dw, (unsigned int)bbits(h0) | ((unsigned int)bbits(h1v) << 16));
        ast(prow + (LOOF >> 1) + dw,
            (unsigned int)bbits(blo(v[0], h0)) | ((unsigned int)bbits(blo(v[1], h1v)) << 16));
        if (t == T - 1) {
          int hg = nt1 * 8 + 2 * ppi;
          h1f[(m0 + ml) * H + hg]     = v[0];  c1f[(m0 + ml) * H + hg]     = creg[0];
          h1f[(m0 + ml) * H + hg + 1] = v[1];  c1f[(m0 + ml) * H + hg + 1] = creg[1];
        }
      }
      cnt_add(hcnt);                        // h1 slice published (drains win+h)
    }
  } else {
    // ========== G2: lstm2 ==========
    const int g = gid - 128;
    const int nt2 = g >> 1, mh = g & 1;
    const int n0 = nt2 * 32, m0 = mh * 64;
    int* hcnt  = ctl + mh * 32;
    int* h2cnt = ctl + 128 + mh * 32;
    __hip_bfloat16* smWh = (__hip_bfloat16*)(sm + O_WH2);
    __hip_bfloat16* smWl = (__hip_bfloat16*)(sm + O_WL2);
    float* Gsm = (float*)(sm + O_GS2);
    float* bia = (float*)(sm + O_BI2);

    for (int i = tid; i < 32 * 136; i += 256) {
      int r = i / 136, c8 = (i - r * 136) * 8;
      *(short8*)(smWh + r * KW2P + c8) = *(const short8*)(wc2  + (size_t)(n0 + r) * K2 + c8);
      *(short8*)(smWl + r * KW2P + c8) = *(const short8*)(wc2l + (size_t)(n0 + r) * K2 + c8);
    }
    if (tid < 32) bia[tid] = bi2[n0 + tid];
    __syncthreads();

    float creg[2];
    {
      int ml = tid >> 2, ppi = tid & 3;
      creg[0] = c2init[(m0 + ml) * H + nt2 * 8 + 2 * ppi + 0];
      creg[1] = c2init[(m0 + ml) * H + nt2 * 8 + 2 * ppi + 1];
    }

    const __hip_bfloat16* W0h = smWh + lm * KW2P;
    const __hip_bfloat16* W1h = smWh + (16 + lm) * KW2P;
    const __hip_bfloat16* W0l = smWl + lm * KW2P;
    const __hip_bfloat16* W1l = smWl + (16 + lm) * KW2P;

    for (int t = 0; t < T; ++t) {
      __hip_bfloat16* S1 = fxHL + (size_t)(t + 1) * SLOTE;
      __hip_bfloat16* S2 = fxHL + (size_t)(t + 2) * SLOTE;
      const __hip_bfloat16* Ar = S1 + (size_t)(m0 + wv * 16 + lm) * SLOTW;

      // own-half h2_{t-1} complete in S1 -> prefetch h2-part A (hi only)
      waitcnt_ge(h2cnt, 64 * t);
      short8 pv2[16];
      #pragma unroll
      for (int c = 0; c < 16; ++c)
        pv2[c] = *(const short8*)(Ar + (K1C + c) * 32 + lk);
      floatx4 a0 = {0.f, 0.f, 0.f, 0.f}, a1 = a0;
      #pragma unroll
      for (int c = 0; c < 16; ++c) {
        int col = (K1C + c) * 32 + lk;
        short8 vb0 = *(const short8*)(W0h + col);
        short8 vb1 = *(const short8*)(W1h + col);
        short8 ub0 = *(const short8*)(W0l + col);
        short8 ub1 = *(const short8*)(W1l + col);
        a0 = __builtin_amdgcn_mfma_f32_16x16x32_bf16(pv2[c], vb0, a0, 0, 0, 0);
        a1 = __builtin_amdgcn_mfma_f32_16x16x32_bf16(pv2[c], vb1, a1, 0, 0, 0);
        a0 = __builtin_amdgcn_mfma_f32_16x16x32_bf16(pv2[c], ub0, a0, 0, 0, 0);
        a1 = __builtin_amdgcn_mfma_f32_16x16x32_bf16(pv2[c], ub1, a1, 0, 0, 0);
      }
      // win_t and h1_t in S1: hcnt covers both (win stores drained before add)
      waitcnt_ge(hcnt, 64 * (t + 1));
      short8 qv[18], qu[18];
      #pragma unroll
      for (int c = 0; c < 18; ++c) {
        qv[c] = *(const short8*)(Ar + c * 32 + lk);
        qu[c] = *(const short8*)(Ar + LOOF + c * 32 + lk);
      }
      #pragma unroll
      for (int c = 0; c < 18; ++c) {
        int col = c * 32 + lk;
        short8 vb0 = *(const short8*)(W0h + col);
        short8 vb1 = *(const short8*)(W1h + col);
        short8 ub0 = *(const short8*)(W0l + col);
        short8 ub1 = *(const short8*)(W1l + col);
        a0 = __builtin_amdgcn_mfma_f32_16x16x32_bf16(qv[c], vb0, a0, 0, 0, 0);
        a1 = __builtin_amdgcn_mfma_f32_16x16x32_bf16(qv[c], vb1, a1, 0, 0, 0);
        a0 = __builtin_amdgcn_mfma_f32_16x16x32_bf16(qv[c], ub0, a0, 0, 0, 0);
        a1 = __builtin_amdgcn_mfma_f32_16x16x32_bf16(qv[c], ub1, a1, 0, 0, 0);
        a0 = __builtin_amdgcn_mfma_f32_16x16x32_bf16(qu[c], vb0, a0, 0, 0, 0);
        a1 = __builtin_amdgcn_mfma_f32_16x16x32_bf16(qu[c], vb1, a1, 0, 0, 0);
      }
      store_gsm(tid, Gsm, a0, a1);
      __syncthreads();

      {
        int ml = tid >> 2, ppi = tid & 3;
        float v[2];
        #pragma unroll
        for (int j = 0; j < 2; ++j) {
          int nl = ppi * 8 + j * 4;
          float gi = Gsm[(nl + 0) * 65 + ml] + bia[nl + 0];
          float gf = Gsm[(nl + 1) * 65 + ml] + bia[nl + 1];
          float gg = Gsm[(nl + 2) * 65 + ml] + bia[nl + 2];
          float go = Gsm[(nl + 3) * 65 + ml] + bia[nl + 3];
          float ig = 1.f / (1.f + expf(-gi));
          float fg = 1.f / (1.f + expf(-gf));
          float gt = tanhf(gg);
          float og = 1.f / (1.f + expf(-go));
          float cn = fg * creg[j] + ig * gt;
          v[j] = og * tanhf(cn);
          creg[j] = cn;
        }
        __hip_bfloat16 h0 = bhi(v[0]), h1v = bhi(v[1]);
        unsigned int* prow = (unsigned int*)(S2 + (size_t)(m0 + ml) * SLOTW);
        int dw = 288 + nt2 * 4 + ppi;      // hi dword of cols {576+nt2*8+2p, +1}
        ast(prow + dw, (unsigned int)bbits(h0) | ((unsigned int)bbits(h1v) << 16));
        if (t == T - 1) {
          int hg = nt2 * 8 + 2 * ppi;
          h2f[(m0 + ml) * H + hg]     = v[0];  c2f[(m0 + ml) * H + hg]     = creg[0];
          h2f[(m0 + ml) * H + hg + 1] = v[1];  c2f[(m0 + ml) * H + hg + 1] = creg[1];
        }
      }
      cnt_add(h2cnt);                       // h2 slice published
    }
  }
}

// ---------------- final GEMM: out[BT x 121] = h2 @ W2^T + b2 ----------------
__global__ __launch_bounds__(256) void k_out(
    const __hip_bfloat16* __restrict__ fxHL, const __hip_bfloat16* __restrict__ w2b,
    const float* __restrict__ b2, float* __restrict__ dout)
{
  int bid = blockIdx.x, tid = threadIdx.x;
  int mblk = bid >> 1, nblk = bid & 1;
  int wv = tid >> 6, lane = tid & 63;
  int lm = lane & 15, lk = (lane >> 4) << 3;
  int m0 = mblk * 128 + wv * 32;
  int n0 = nblk * 64;
  int r0 = m0 + lm, r1 = m0 + 16 + lm;
  const __hip_bfloat16* a0p = fxHL + (size_t)((r0 & 255) + 2) * SLOTE + (r0 >> 8) * SLOTW + 576;
  const __hip_bfloat16* a1p = fxHL + (size_t)((r1 & 255) + 2) * SLOTE + (r1 >> 8) * SLOTW + 576;
  floatx4 zz = {0.f, 0.f, 0.f, 0.f};
  floatx4 acc[2][4];
  #pragma unroll
  for (int mt = 0; mt < 2; ++mt)
    #pragma unroll
    for (int nt = 0; nt < 4; ++nt) acc[mt][nt] = zz;
  #pragma unroll
  for (int c = 0; c < 16; ++c) {
    int col = c * 32 + lk;
    short8 va0 = *(const short8*)(a0p + col);
    short8 va1 = *(const short8*)(a1p + col);
    short8 vb[4];
    #pragma unroll
    for (int nt = 0; nt < 4; ++nt)
      vb[nt] = *(const short8*)(w2b + (size_t)(n0 + nt * 16 + lm) * 512 + col);
    #pragma unroll
    for (int nt = 0; nt < 4; ++nt) {
      acc[0][nt] = __builtin_amdgcn_mfma_f32_16x16x32_bf16(va0, vb[nt], acc[0][nt], 0, 0, 0);
      acc[1][nt] = __builtin_amdgcn_mfma_f32_16x16x32_bf16(va1, vb[nt], acc[1][nt], 0, 0, 0);
    }
  }
  int rr = (lane >> 4) << 2;
  #pragma unroll
  for (int mt = 0; mt < 2; ++mt)
    #pragma unroll
    for (int nt = 0; nt < 4; ++nt)
      #pragma unroll
      for (int r = 0; r < 4; ++r) {
        int m = m0 + mt * 16 + rr + r;
        int n = n0 + nt * 16 + lm;
        if (n < OUTW) dout[(size_t)m * OUTW + n] = acc[mt][nt][r] + b2[n];
      }
}

// ---------------- host ----------------
extern "C" void kernel_launch(void* const* d_in, const int* in_sizes, int n_in,
                              void* d_out, int out_size, void* d_ws, size_t ws_size,
                              hipStream_t stream)
{
  (void)in_sizes; (void)n_in; (void)out_size; (void)ws_size;
  const float* x    = (const float*)d_in[0];
  const float* sent = (const float*)d_in[1];
  const float* h1h  = (const float*)d_in[2];
  const float* h1c  = (const float*)d_in[3];
  const float* h2h  = (const float*)d_in[4];
  const float* h2c  = (const float*)d_in[5];
  const float* Wihc = (const float*)d_in[6];
  const float* Whhc = (const float*)d_in[7];
  const float* bc   = (const float*)d_in[8];
  const float* Wihl = (const float*)d_in[9];
  const float* Whhl = (const float*)d_in[10];
  const float* bl   = (const float*)d_in[11];
  const float* W1   = (const float*)d_in[12];
  const float* b1   = (const float*)d_in[13];
  const float* W2   = (const float*)d_in[14];
  const float* b2   = (const float*)d_in[15];

  float* out = (float*)d_out;
  float* h1f = out + (size_t)B * T * OUTW;
  float* c1f = h1f + (size_t)B * H;
  float* h2f = c1f + (size_t)B * H;
  float* c2f = h2f + (size_t)B * H;

  char* p = (char*)d_ws;
  auto carve = [&](size_t bytes) { char* r = p; p += (bytes + 255) & ~(size_t)255; return r; };
  __hip_bfloat16* fxHL = (__hip_bfloat16*)carve((size_t)NSLOT * SLOTE * 2);
  __hip_bfloat16* wc1  = (__hip_bfloat16*)carve((size_t)NG * K1 * 2);
  __hip_bfloat16* wc1l = (__hip_bfloat16*)carve((size_t)NG * K1 * 2);
  __hip_bfloat16* wc2  = (__hip_bfloat16*)carve((size_t)NG * K2 * 2);
  __hip_bfloat16* wc2l = (__hip_bfloat16*)carve((size_t)NG * K2 * 2);
  __hip_bfloat16* w2b  = (__hip_bfloat16*)carve((size_t)128 * 512 * 2);
  float* bi1 = (float*)carve((size_t)NG * 4);
  float* bi2 = (float*)carve((size_t)NG * 4);
  int*   ctl = (int*)carve((size_t)512 * 4);

  static bool attr_set = false;
  if (!attr_set) {
    (void)hipFuncSetAttribute((const void*)k_persist,
                              hipFuncAttributeMaxDynamicSharedMemorySize, LDS_SZ);
    attr_set = true;
  }

  k_pre<<<14226, 256, 0, stream>>>(x, h1h, h2h, Wihc, Whhc, bc, Wihl, Whhl, bl, W2,
                                   fxHL, wc1, wc1l, wc2, wc2l, w2b, bi1, bi2, ctl);
  k_persist<<<256, 256, LDS_SZ, stream>>>(fxHL, wc1, wc1l, wc2, wc2l, bi1, bi2,
                                          h1c, h2c, x, sent, W1, b1, ctl,
                                          h1f, c1f, h2f, c2f);
  k_out<<<512, 256, 0, stream>>>(fxHL, w2b, b2, out);
}